// Round 2
// 285.313 us; speedup vs baseline: 1.0235x; 1.0235x over previous
//
#include <hip/hip_runtime.h>
#include <hip/hip_bf16.h>
#include <math.h>

// Problem constants
#define B_   4
#define N_   2048
#define DIM_ 1024
#define H_   16
#define DH_  64
#define E3_  3072   // 3*H*DH

typedef __attribute__((ext_vector_type(8)))  short s8v;   // 8 bf16 (4 VGPRs)
typedef __attribute__((ext_vector_type(4)))  float f4v;   // 16x16 MFMA accumulator
typedef __attribute__((ext_vector_type(16))) float f16v;  // 32x32 MFMA accumulator

// fast fp32->bf16: round-half-up (adds 0.5 ulp then truncate). 2 VALU ops.
__device__ __forceinline__ unsigned short f2bf_fast(float f) {
    return (unsigned short)((__builtin_bit_cast(unsigned int, f) + 0x8000u) >> 16);
}
// pack two fp32 -> two bf16 in one u32 via v_perm_b32 (3 VALU ops total)
__device__ __forceinline__ unsigned int pkbf(float a, float b) {
    unsigned int ua = __builtin_bit_cast(unsigned int, a) + 0x8000u;
    unsigned int ub = __builtin_bit_cast(unsigned int, b) + 0x8000u;
    return __builtin_amdgcn_perm(ub, ua, 0x07060302);
}
// single-instruction pack: dst.lo = bf16(a), dst.hi = bf16(b)  (RNE)
__device__ __forceinline__ unsigned int cvtpk(float a, float b) {
    unsigned int r;
    asm("v_cvt_pk_bf16_f32 %0, %1, %2" : "=v"(r) : "v"(a), "v"(b));
    return r;
}
// v_permlane32_swap_b32: after execution
//   a' = [a(lanes 0:31) | b(lanes 0:31)],  b' = [a(lanes 32:63) | b(lanes 32:63)]
// (asm-only form: instruction is HW-verified on gfx950; builtin signature
//  varies across ROCm versions, so we avoid it)
__device__ __forceinline__ uint2 pl32(unsigned int a, unsigned int b) {
    asm volatile("v_permlane32_swap_b32 %0, %1" : "+v"(a), "+v"(b));
    return make_uint2(a, b);
}

// async global->LDS, 16 B per lane; LDS dest = wave-uniform base + lane*16
__device__ __forceinline__ void gload_lds16(const void* g, void* l) {
    __builtin_amdgcn_global_load_lds(
        (const __attribute__((address_space(1))) unsigned int*)(uintptr_t)g,
        (__attribute__((address_space(3))) unsigned int*)(uintptr_t)l,
        16, 0, 0);
}

// ---------------------------------------------------------------------------
// fp32 -> bf16 convert (perm-packed)
// ---------------------------------------------------------------------------
__global__ __launch_bounds__(256) void cvt_bf16(
    const float* __restrict__ in, unsigned short* __restrict__ out, int n)
{
    const int i = (blockIdx.x * 256 + threadIdx.x) * 4;
    if (i < n) {
        float4 v = *(const float4*)(in + i);
        uint2 pk;
        pk.x = pkbf(v.x, v.y);
        pk.y = pkbf(v.z, v.w);
        *(uint2*)(out + i) = pk;
    }
}

// ---------------------------------------------------------------------------
// bf16 MFMA GEMM, m97 structure: C[M,Nc] = A[M,K] @ Bw[Nc,K]^T
// 128x128 tile, BK=32, 256 thr = 4 waves (2x2), each wave 64x64 via 4x4
// 16x16x32 MFMAs. global_load_lds width 16, no LDS padding (required).
// MODE 0: out = bf16 qkv; Q-third pre-scaled by 0.125*log2(e);
//         V-third redirected to vT[b,h,d,n] (uint2-packed stores along n).
// MODE 1: out = fp32 + bias.
// ---------------------------------------------------------------------------
template<int MODE>
__global__ __launch_bounds__(256) void gemm_mfma(
    const unsigned short* __restrict__ A,
    const unsigned short* __restrict__ Bw,
    const float* __restrict__ bias,
    unsigned short* __restrict__ Cb,   // MODE 0: qkv bf16 [M][Nc]
    unsigned short* __restrict__ Vt,   // MODE 0: [B*H][64][2048]
    float* __restrict__ Cf,            // MODE 1: fp32 [M][Nc]
    int M, int Nc, int K)
{
    __shared__ unsigned short As[128 * 32];
    __shared__ unsigned short Bs[128 * 32];

    const int tid  = threadIdx.x;
    const int w    = tid >> 6;
    const int lane = tid & 63;
    const int quad = lane >> 4;
    const int l15  = lane & 15;
    const int wm   = w & 1, wn = w >> 1;
    const int m0   = blockIdx.y * 128, n0 = blockIdx.x * 128;

    const int srow = lane >> 2;        // 0..15
    const int sch  = (lane & 3) * 8;   // k element offset 0,8,16,24

    f4v acc[4][4];
    #pragma unroll
    for (int i = 0; i < 4; i++)
        #pragma unroll
        for (int j = 0; j < 4; j++) acc[i][j] = (f4v){0.f, 0.f, 0.f, 0.f};

    for (int k0 = 0; k0 < K; k0 += 32) {
        __syncthreads();   // fragment reads of prev iter complete
        #pragma unroll
        for (int i = 0; i < 2; i++) {
            const int rbase = w * 32 + i * 16;   // 16 rows per instruction
            gload_lds16(A  + (size_t)(m0 + rbase + srow) * K + k0 + sch,
                        &As[rbase * 32]);
            gload_lds16(Bw + (size_t)(n0 + rbase + srow) * K + k0 + sch,
                        &Bs[rbase * 32]);
        }
        __syncthreads();   // drains vmcnt -> LDS visible

        s8v af[4], bf[4];
        #pragma unroll
        for (int i = 0; i < 4; i++) {
            af[i] = *(const s8v*)&As[(wm * 64 + i * 16 + l15) * 32 + quad * 8];
            bf[i] = *(const s8v*)&Bs[(wn * 64 + i * 16 + l15) * 32 + quad * 8];
        }
        #pragma unroll
        for (int ms = 0; ms < 4; ms++)
            #pragma unroll
            for (int ns = 0; ns < 4; ns++)
                acc[ms][ns] = __builtin_amdgcn_mfma_f32_16x16x32_bf16(
                    af[ms], bf[ns], acc[ms][ns], 0, 0, 0);
    }

    // epilogue: C/D layout col = l15, row = quad*4 + r
    if (MODE == 0) {
        #pragma unroll
        for (int ns = 0; ns < 4; ns++) {
            const int colb = n0 + wn * 64 + ns * 16;   // wave-uniform
            if (colb < 2048) {
                // fold softmax scale*log2(e) into Q columns
                const float mul = (colb < 1024) ? 0.18033688011112042f : 1.0f;
                #pragma unroll
                for (int ms = 0; ms < 4; ms++)
                    #pragma unroll
                    for (int r = 0; r < 4; r++) {
                        const int row = m0 + wm * 64 + ms * 16 + quad * 4 + r;
                        Cb[(size_t)row * Nc + colb + l15] = f2bf_fast(acc[ms][ns][r] * mul);
                    }
            } else {
                const int e = colb + l15 - 2048;
                const int h = e >> 6, d = e & 63;         // wave-uniform h
                #pragma unroll
                for (int ms = 0; ms < 4; ms++) {
                    const int row = m0 + wm * 64 + ms * 16 + quad * 4; // r=0
                    const int b = row >> 11, n = row & 2047;          // 4-aligned
                    uint2 pk;
                    pk.x = pkbf(acc[ms][ns][0], acc[ms][ns][1]);
                    pk.y = pkbf(acc[ms][ns][2], acc[ms][ns][3]);
                    *(uint2*)&Vt[(((size_t)b * 16 + h) * 64 + d) * 2048 + n] = pk;
                }
            }
        }
    } else {
        #pragma unroll
        for (int ns = 0; ns < 4; ns++) {
            const float bz = bias[n0 + wn * 64 + ns * 16 + l15];
            #pragma unroll
            for (int ms = 0; ms < 4; ms++)
                #pragma unroll
                for (int r = 0; r < 4; r++) {
                    const int row = m0 + wm * 64 + ms * 16 + quad * 4 + r;
                    Cf[(size_t)row * Nc + n0 + wn * 64 + ns * 16 + l15] =
                        acc[ms][ns][r] + bz;
                }
        }
    }
}

// ---------------------------------------------------------------------------
// MFMA flash attention v6: 32x32x16 MFMAs, in-register P (no Ps LDS).
// - 4 waves x 64 q-rows = 256 q/block; grid (8,64)=512 blocks = 2/CU.
// - S^T = K·Q^T (32x32x16): lane holds 16 P-values of ONE q-row (col=lane&31),
//   keys (reg&3)+8*(reg>>2)+4*(lane>>5). exp2 -> v_cvt_pk_bf16_f32 ->
//   permlane32_swap builds PV A-fragments entirely in-register (T12).
// - row-sum l = P·ones MFMA: its C layout matches O's exactly -> zero-cost
//   normalization (no cross-lane redistribution).
// - K/V LDS tiles [64][64] XOR-swizzled (col8 ^= (row&7)*8) on BOTH write and
//   read sides: stride-128B rows would otherwise be a 32-way bank conflict.
// - K/V double-buffered, reg-prefetch, one barrier per tile (as v5).
// - LDS 32 KB (was 73.7); s_setprio(1) around MFMA clusters (T5).
// qkv bf16 [m][3072] (Q pre-scaled by 0.125*log2e); vT[b*16+h][d][n] bf16.
// ---------------------------------------------------------------------------
__global__ __launch_bounds__(256, 2) void attn_mfma(
    const unsigned short* __restrict__ qkv,
    const unsigned short* __restrict__ vT,
    unsigned short* __restrict__ ao)
{
    __shared__ __align__(16) unsigned short Ks[2][64][64];   // [buf][key][d] swz
    __shared__ __align__(16) unsigned short Vs[2][64][64];   // [buf][d][key] swz

    const int tid  = threadIdx.x;
    const int w    = tid >> 6;          // 0..3
    const int lane = tid & 63;
    const int l31  = lane & 31;
    const int hi5  = lane >> 5;         // 0/1
    const int h8   = hi5 * 8;

    const int bh = blockIdx.y;
    const int b  = bh >> 4;
    const int h  = bh & 15;
    const int q0 = blockIdx.x * 256;    // 256 q-rows per block

    const unsigned short* qp  = qkv + (size_t)b * N_ * E3_ + (size_t)h * DH_;
    const unsigned short* kp  = qp + 1024;
    const unsigned short* vtp = vT + (size_t)bh * 64 * 2048;

    // staging: 64 rows x 8 chunks of 16B per tensor per tile; 2 rows/thread
    const int srow0 = tid >> 3;               // 0..31
    const int srow1 = srow0 + 32;             // 32..63
    const int sc    = tid & 7;                // chunk 0..7
    const int sw0   = (sc ^ (srow0 & 7)) * 8; // swizzled col (shorts)
    const int sw1   = (sc ^ (srow1 & 7)) * 8;

    // Q B-fragments straight from global (one-time): B[k=d][col=qrow]
    s8v bq[2][4];
    #pragma unroll
    for (int sub = 0; sub < 2; sub++) {
        const unsigned short* qrow =
            qp + (size_t)(q0 + w * 64 + sub * 32 + l31) * E3_;
        #pragma unroll
        for (int ks = 0; ks < 4; ks++)
            bq[sub][ks] = *(const s8v*)(qrow + ks * 16 + h8);
    }

    // ones B-fragment (bf16 1.0) for row-sum MFMA
    s8v ones;
    #pragma unroll
    for (int i = 0; i < 8; i++) ones[i] = (short)0x3F80;

    const f16v fzero = {0.f,0.f,0.f,0.f,0.f,0.f,0.f,0.f,
                        0.f,0.f,0.f,0.f,0.f,0.f,0.f,0.f};
    f16v o[2][2];      // [q-subtile][d-tile]
    o[0][0] = fzero; o[0][1] = fzero; o[1][0] = fzero; o[1][1] = fzero;
    f16v lc[2];        // row-sums, layout-matched to o
    lc[0] = fzero; lc[1] = fzero;

    // ---- prologue: stage tile 0 into buffer 0 (swizzled) ----
    {
        s8v k0 = *(const s8v*)(kp  + (size_t)srow0 * E3_  + sc * 8);
        s8v k1 = *(const s8v*)(kp  + (size_t)srow1 * E3_  + sc * 8);
        s8v v0 = *(const s8v*)(vtp + (size_t)srow0 * 2048 + sc * 8);
        s8v v1 = *(const s8v*)(vtp + (size_t)srow1 * 2048 + sc * 8);
        *(s8v*)&Ks[0][srow0][sw0] = k0;
        *(s8v*)&Ks[0][srow1][sw1] = k1;
        *(s8v*)&Vs[0][srow0][sw0] = v0;
        *(s8v*)&Vs[0][srow1][sw1] = v1;
    }
    __syncthreads();

    for (int kt = 0; kt < N_ / 64; kt++) {
        const int cur = kt & 1;
        const bool pre = (kt + 1 < N_ / 64);

        // ---- issue next tile's global loads (latency hidden by compute) ----
        s8v pk0, pk1, pv0, pv1;
        if (pre) {
            const int kn = (kt + 1) * 64;
            pk0 = *(const s8v*)(kp  + (size_t)(kn + srow0) * E3_ + sc * 8);
            pk1 = *(const s8v*)(kp  + (size_t)(kn + srow1) * E3_ + sc * 8);
            pv0 = *(const s8v*)(vtp + (size_t)srow0 * 2048 + kn + sc * 8);
            pv1 = *(const s8v*)(vtp + (size_t)srow1 * 2048 + kn + sc * 8);
        }

        #pragma unroll
        for (int ksub = 0; ksub < 2; ksub++) {
            // K A-fragments: A[row=key][k=d], row = ksub*32 + l31
            const int krow = ksub * 32 + l31;
            const int ksw  = (krow & 7) * 8;
            s8v ak[4];
            #pragma unroll
            for (int ks = 0; ks < 4; ks++)
                ak[ks] = *(const s8v*)&Ks[cur][krow][(ks * 16 + h8) ^ ksw];

            // S^T per q-subtile -> exp2 -> in-register P A-fragments
            s8v pa[2][2];   // [sub][kstep within ksub]
            #pragma unroll
            for (int sub = 0; sub < 2; sub++) {
                f16v st = fzero;
                __builtin_amdgcn_s_setprio(1);
                st = __builtin_amdgcn_mfma_f32_32x32x16_bf16(ak[0], bq[sub][0], st, 0, 0, 0);
                st = __builtin_amdgcn_mfma_f32_32x32x16_bf16(ak[1], bq[sub][1], st, 0, 0, 0);
                st = __builtin_amdgcn_mfma_f32_32x32x16_bf16(ak[2], bq[sub][2], st, 0, 0, 0);
                st = __builtin_amdgcn_mfma_f32_32x32x16_bf16(ak[3], bq[sub][3], st, 0, 0, 0);
                __builtin_amdgcn_s_setprio(0);

                float pe[16];
                #pragma unroll
                for (int i = 0; i < 16; i++)
                    pe[i] = __builtin_amdgcn_exp2f(st[i]);

                // pack pairs, swap halves: lane gets its q-row's keys
                // lo lane holds keys {0-3,8-11,16-19,24-27}(+ksub*32), hi +4
                union { s8v v; unsigned int u[4]; } f0, f1;
                uint2 r;
                r = pl32(cvtpk(pe[0],  pe[1]),  cvtpk(pe[4],  pe[5]));
                f0.u[0] = r.x; f0.u[2] = r.y;
                r = pl32(cvtpk(pe[2],  pe[3]),  cvtpk(pe[6],  pe[7]));
                f0.u[1] = r.x; f0.u[3] = r.y;
                r = pl32(cvtpk(pe[8],  pe[9]),  cvtpk(pe[12], pe[13]));
                f1.u[0] = r.x; f1.u[2] = r.y;
                r = pl32(cvtpk(pe[10], pe[11]), cvtpk(pe[14], pe[15]));
                f1.u[1] = r.x; f1.u[3] = r.y;
                pa[sub][0] = f0.v;   // keys ksub*32 + 0..15
                pa[sub][1] = f1.v;   // keys ksub*32 + 16..31
            }

            // ---- O += P V ; l += P @ ones ----
            #pragma unroll
            for (int j = 0; j < 2; j++) {
                const int kbase = (ksub * 2 + j) * 16 + h8;
                const int vsw   = (l31 & 7) * 8;
                s8v bv0 = *(const s8v*)&Vs[cur][l31     ][kbase ^ vsw];
                s8v bv1 = *(const s8v*)&Vs[cur][32 + l31][kbase ^ vsw];
                __builtin_amdgcn_s_setprio(1);
                o[0][0] = __builtin_amdgcn_mfma_f32_32x32x16_bf16(pa[0][j], bv0, o[0][0], 0, 0, 0);
                o[1][0] = __builtin_amdgcn_mfma_f32_32x32x16_bf16(pa[1][j], bv0, o[1][0], 0, 0, 0);
                o[0][1] = __builtin_amdgcn_mfma_f32_32x32x16_bf16(pa[0][j], bv1, o[0][1], 0, 0, 0);
                o[1][1] = __builtin_amdgcn_mfma_f32_32x32x16_bf16(pa[1][j], bv1, o[1][1], 0, 0, 0);
                lc[0]   = __builtin_amdgcn_mfma_f32_32x32x16_bf16(pa[0][j], ones, lc[0], 0, 0, 0);
                lc[1]   = __builtin_amdgcn_mfma_f32_32x32x16_bf16(pa[1][j], ones, lc[1], 0, 0, 0);
                __builtin_amdgcn_s_setprio(0);
            }
        }

        // ---- write prefetched tile into back buffer; single barrier ----
        if (pre) {
            const int nxt = cur ^ 1;
            *(s8v*)&Ks[nxt][srow0][sw0] = pk0;
            *(s8v*)&Ks[nxt][srow1][sw1] = pk1;
            *(s8v*)&Vs[nxt][srow0][sw0] = pv0;
            *(s8v*)&Vs[nxt][srow1][sw1] = pv1;
        }
        __syncthreads();
    }

    // normalize + write ao bf16 [m][1024]; lc layout == o layout
    #pragma unroll
    for (int sub = 0; sub < 2; sub++) {
        float inv[16];
        #pragma unroll
        for (int r = 0; r < 16; r++) inv[r] = 1.f / lc[sub][r];
        #pragma unroll
        for (int dt = 0; dt < 2; dt++)
            #pragma unroll
            for (int r = 0; r < 16; r++) {
                const int qrow = q0 + w * 64 + sub * 32 + (r & 3) + 8 * (r >> 2) + 4 * hi5;
                ao[((size_t)b * N_ + qrow) * (H_ * DH_) + h * DH_ + dt * 32 + l31] =
                    f2bf_fast(o[sub][dt][r] * inv[r]);
            }
    }
}

// ---------------------------------------------------------------------------
// Launch
// ---------------------------------------------------------------------------
extern "C" void kernel_launch(void* const* d_in, const int* in_sizes, int n_in,
                              void* d_out, int out_size, void* d_ws, size_t ws_size,
                              hipStream_t stream) {
    const float* x     = (const float*)d_in[0];   // [B,N,DIM]
    const float* w_qkv = (const float*)d_in[1];   // [3072, 1024]
    const float* w_out = (const float*)d_in[2];   // [1024, 1024]
    const float* b_out = (const float*)d_in[3];   // [1024]
    float* out = (float*)d_out;                   // [B,N,DIM] fp32

    char* ws = (char*)d_ws;
    unsigned short* x_bf    = (unsigned short*)(ws);                        // 16 MB
    unsigned short* wqkv_bf = (unsigned short*)(ws + (((size_t)16) << 20)); //  6 MB
    unsigned short* wout_bf = (unsigned short*)(ws + (((size_t)22) << 20)); //  2 MB
    unsigned short* qkv_bf  = (unsigned short*)(ws + (((size_t)24) << 20)); // 48 MB
    unsigned short* vT      = (unsigned short*)(ws + (((size_t)72) << 20)); // 16 MB
    unsigned short* ao_bf   = (unsigned short*)(ws + (((size_t)88) << 20)); // 16 MB

    const int M = B_ * N_;   // 8192

    // 0) input conversions fp32 -> bf16
    cvt_bf16<<<(M * DIM_) / 1024, 256, 0, stream>>>(x, x_bf, M * DIM_);
    cvt_bf16<<<(E3_ * DIM_) / 1024, 256, 0, stream>>>(w_qkv, wqkv_bf, E3_ * DIM_);
    cvt_bf16<<<(DIM_ * DIM_) / 1024, 256, 0, stream>>>(w_out, wout_bf, DIM_ * DIM_);

    // 1) QKV projection (bf16 MFMA): Q pre-scaled, V redirected to vT
    {
        dim3 grid(E3_ / 128, M / 128);   // (24, 64)
        gemm_mfma<0><<<grid, 256, 0, stream>>>(x_bf, wqkv_bf, nullptr,
                                               qkv_bf, vT, nullptr, M, E3_, DIM_);
    }
    // 2) attention (bf16 32x32 MFMA, in-register P, swizzled K/V, dbuf)
    {
        dim3 grid(N_ / 256, B_ * H_);    // (8, 64) = 512 blocks = 2/CU
        attn_mfma<<<grid, 256, 0, stream>>>(qkv_bf, vT, ao_bf);
    }
    // 3) out projection (bf16 MFMA, fp32 + bias out)
    {
        dim3 grid(DIM_ / 128, M / 128);  // (8, 64)
        gemm_mfma<1><<<grid, 256, 0, stream>>>(ao_bf, wout_bf, b_out,
                                               nullptr, nullptr, out, M, DIM_, DIM_);
    }
    (void)in_sizes; (void)n_in; (void)out_size; (void)ws_size;
}

// Round 3
// 276.341 us; speedup vs baseline: 1.0568x; 1.0325x over previous
//
#include <hip/hip_runtime.h>
#include <hip/hip_bf16.h>
#include <math.h>

// Problem constants
#define B_   4
#define N_   2048
#define DIM_ 1024
#define H_   16
#define DH_  64
#define E3_  3072   // 3*H*DH

typedef __attribute__((ext_vector_type(8)))  short s8v;   // 8 bf16 (4 VGPRs)
typedef __attribute__((ext_vector_type(4)))  float f4v;   // 16x16 MFMA accumulator
typedef __attribute__((ext_vector_type(16))) float f16v;  // 32x32 MFMA accumulator

// fast fp32->bf16: round-half-up (adds 0.5 ulp then truncate). 2 VALU ops.
__device__ __forceinline__ unsigned short f2bf_fast(float f) {
    return (unsigned short)((__builtin_bit_cast(unsigned int, f) + 0x8000u) >> 16);
}
// pack two fp32 -> two bf16 in one u32 via v_perm_b32 (3 VALU ops total)
__device__ __forceinline__ unsigned int pkbf(float a, float b) {
    unsigned int ua = __builtin_bit_cast(unsigned int, a) + 0x8000u;
    unsigned int ub = __builtin_bit_cast(unsigned int, b) + 0x8000u;
    return __builtin_amdgcn_perm(ub, ua, 0x07060302);
}
// single-instruction pack: dst.lo = bf16(a), dst.hi = bf16(b)  (RNE)
__device__ __forceinline__ unsigned int cvtpk(float a, float b) {
    unsigned int r;
    asm("v_cvt_pk_bf16_f32 %0, %1, %2" : "=v"(r) : "v"(a), "v"(b));
    return r;
}
// v_permlane32_swap_b32: after execution
//   a' = [a(lanes 0:31) | b(lanes 0:31)],  b' = [a(lanes 32:63) | b(lanes 32:63)]
__device__ __forceinline__ uint2 pl32(unsigned int a, unsigned int b) {
    asm volatile("v_permlane32_swap_b32 %0, %1" : "+v"(a), "+v"(b));
    return make_uint2(a, b);
}

// async global->LDS, 16 B per lane; LDS dest = wave-uniform base + lane*16
__device__ __forceinline__ void gload_lds16(const void* g, void* l) {
    __builtin_amdgcn_global_load_lds(
        (const __attribute__((address_space(1))) unsigned int*)(uintptr_t)g,
        (__attribute__((address_space(3))) unsigned int*)(uintptr_t)l,
        16, 0, 0);
}

// ---------------------------------------------------------------------------
// fp32 -> bf16 convert (perm-packed)
// ---------------------------------------------------------------------------
__global__ __launch_bounds__(256) void cvt_bf16(
    const float* __restrict__ in, unsigned short* __restrict__ out, int n)
{
    const int i = (blockIdx.x * 256 + threadIdx.x) * 4;
    if (i < n) {
        float4 v = *(const float4*)(in + i);
        uint2 pk;
        pk.x = pkbf(v.x, v.y);
        pk.y = pkbf(v.z, v.w);
        *(uint2*)(out + i) = pk;
    }
}

// ---------------------------------------------------------------------------
// bf16 MFMA GEMM, m97 structure: C[M,Nc] = A[M,K] @ Bw[Nc,K]^T
// 128x128 tile, BK=32, 256 thr = 4 waves (2x2), each wave 64x64 via 4x4
// 16x16x32 MFMAs. global_load_lds width 16, no LDS padding (required).
// XCD-chunked block swizzle (T1): nwg%8==0 for both call sites.
// MODE 0: out = bf16 qkv; Q-third pre-scaled by 0.125*log2(e);
//         V-third redirected to vT[b,h,d,n] (uint2-packed stores along n).
// MODE 1: out = fp32 + bias.
// ---------------------------------------------------------------------------
template<int MODE>
__global__ __launch_bounds__(256) void gemm_mfma(
    const unsigned short* __restrict__ A,
    const unsigned short* __restrict__ Bw,
    const float* __restrict__ bias,
    unsigned short* __restrict__ Cb,   // MODE 0: qkv bf16 [M][Nc]
    unsigned short* __restrict__ Vt,   // MODE 0: [B*H][64][2048]
    float* __restrict__ Cf,            // MODE 1: fp32 [M][Nc]
    int M, int Nc, int K)
{
    __shared__ unsigned short As[128 * 32];
    __shared__ unsigned short Bs[128 * 32];

    const int tid  = threadIdx.x;
    const int w    = tid >> 6;
    const int lane = tid & 63;
    const int quad = lane >> 4;
    const int l15  = lane & 15;
    const int wm   = w & 1, wn = w >> 1;

    // XCD-chunked swizzle: each XCD gets a contiguous chunk of tile-space
    const int nwx = gridDim.x;
    const int lin = blockIdx.y * nwx + blockIdx.x;
    const int cpx = (nwx * gridDim.y) >> 3;       // nwg/8 (nwg%8==0)
    const int swz = (lin & 7) * cpx + (lin >> 3);
    const int m0  = (swz / nwx) * 128, n0 = (swz % nwx) * 128;

    const int srow = lane >> 2;        // 0..15
    const int sch  = (lane & 3) * 8;   // k element offset 0,8,16,24

    f4v acc[4][4];
    #pragma unroll
    for (int i = 0; i < 4; i++)
        #pragma unroll
        for (int j = 0; j < 4; j++) acc[i][j] = (f4v){0.f, 0.f, 0.f, 0.f};

    for (int k0 = 0; k0 < K; k0 += 32) {
        __syncthreads();   // fragment reads of prev iter complete
        #pragma unroll
        for (int i = 0; i < 2; i++) {
            const int rbase = w * 32 + i * 16;   // 16 rows per instruction
            gload_lds16(A  + (size_t)(m0 + rbase + srow) * K + k0 + sch,
                        &As[rbase * 32]);
            gload_lds16(Bw + (size_t)(n0 + rbase + srow) * K + k0 + sch,
                        &Bs[rbase * 32]);
        }
        __syncthreads();   // drains vmcnt -> LDS visible

        s8v af[4], bf[4];
        #pragma unroll
        for (int i = 0; i < 4; i++) {
            af[i] = *(const s8v*)&As[(wm * 64 + i * 16 + l15) * 32 + quad * 8];
            bf[i] = *(const s8v*)&Bs[(wn * 64 + i * 16 + l15) * 32 + quad * 8];
        }
        #pragma unroll
        for (int ms = 0; ms < 4; ms++)
            #pragma unroll
            for (int ns = 0; ns < 4; ns++)
                acc[ms][ns] = __builtin_amdgcn_mfma_f32_16x16x32_bf16(
                    af[ms], bf[ns], acc[ms][ns], 0, 0, 0);
    }

    // epilogue: C/D layout col = l15, row = quad*4 + r
    if (MODE == 0) {
        #pragma unroll
        for (int ns = 0; ns < 4; ns++) {
            const int colb = n0 + wn * 64 + ns * 16;   // wave-uniform
            if (colb < 2048) {
                // fold softmax scale*log2(e) into Q columns
                const float mul = (colb < 1024) ? 0.18033688011112042f : 1.0f;
                #pragma unroll
                for (int ms = 0; ms < 4; ms++)
                    #pragma unroll
                    for (int r = 0; r < 4; r++) {
                        const int row = m0 + wm * 64 + ms * 16 + quad * 4 + r;
                        Cb[(size_t)row * Nc + colb + l15] = f2bf_fast(acc[ms][ns][r] * mul);
                    }
            } else {
                const int e = colb + l15 - 2048;
                const int h = e >> 6, d = e & 63;         // wave-uniform h
                #pragma unroll
                for (int ms = 0; ms < 4; ms++) {
                    const int row = m0 + wm * 64 + ms * 16 + quad * 4; // r=0
                    const int b = row >> 11, n = row & 2047;          // 4-aligned
                    uint2 pk;
                    pk.x = pkbf(acc[ms][ns][0], acc[ms][ns][1]);
                    pk.y = pkbf(acc[ms][ns][2], acc[ms][ns][3]);
                    *(uint2*)&Vt[(((size_t)b * 16 + h) * 64 + d) * 2048 + n] = pk;
                }
            }
        }
    } else {
        #pragma unroll
        for (int ns = 0; ns < 4; ns++) {
            const float bz = bias[n0 + wn * 64 + ns * 16 + l15];
            #pragma unroll
            for (int ms = 0; ms < 4; ms++)
                #pragma unroll
                for (int r = 0; r < 4; r++) {
                    const int row = m0 + wm * 64 + ms * 16 + quad * 4 + r;
                    Cf[(size_t)row * Nc + n0 + wn * 64 + ns * 16 + l15] =
                        acc[ms][ns][r] + bz;
                }
        }
    }
}

// ---------------------------------------------------------------------------
// MFMA flash attention v7: 32x32x16, in-register P, 8 waves x 32 q-rows.
// - 512-thread blocks, grid (8,64)=512 blocks = 2/CU = 16 waves/CU =
//   4 waves/SIMD (v6 had 2/SIMD; overlap capacity was the limiter:
//   MfmaUtil 41 + VALUBusy 36, ~23% bubbles from the per-wave
//   MFMA->VALU->MFMA serial chain).
// - K/V staged via global_load_lds (2 instr/wave/tile): LDS dest linear,
//   global SOURCE pre-swizzled with the same involution the reads use
//   (chunk ^= row&7) -> no ds_write slots, no prefetch VGPRs (rule #21).
// - S^T = K·Q^T: lane holds its q-row's 16 S values; exp2 -> cvt_pk ->
//   permlane32_swap builds PV A-fragments in-register (T12).
// - l = P·ones MFMA, layout-matched to O -> free normalization.
// - XCD-chunked block swizzle: all 8 blocks of one (b,h) on one XCD ->
//   K/V read once per L2 instead of 8x (FETCH was ~50% K/V re-fetch).
// qkv bf16 [m][3072] (Q pre-scaled by 0.125*log2e); vT[b*16+h][d][n] bf16.
// ---------------------------------------------------------------------------
__global__ __launch_bounds__(512, 4) void attn_mfma(
    const unsigned short* __restrict__ qkv,
    const unsigned short* __restrict__ vT,
    unsigned short* __restrict__ ao)
{
    __shared__ __align__(16) unsigned short Ks[2][64][64];   // [buf][key][d] swz
    __shared__ __align__(16) unsigned short Vs[2][64][64];   // [buf][d][key] swz

    const int tid  = threadIdx.x;
    const int w    = tid >> 6;          // 0..7
    const int lane = tid & 63;
    const int l31  = lane & 31;
    const int hi5  = lane >> 5;         // 0/1
    const int h8   = hi5 * 8;

    // XCD-chunked swizzle over the 512-block grid (8 x-tiles fastest)
    const int lin = blockIdx.y * 8 + blockIdx.x;
    const int swz = (lin & 7) * 64 + (lin >> 3);
    const int bx  = swz & 7;
    const int bh  = swz >> 3;
    const int b   = bh >> 4;
    const int h   = bh & 15;
    const int q0  = bx * 256;           // 256 q-rows per block
    const int qb  = q0 + w * 32;        // 32 q-rows per wave

    const unsigned short* qp  = qkv + (size_t)b * N_ * E3_ + (size_t)h * DH_;
    const unsigned short* kp  = qp + 1024;
    const unsigned short* vtp = vT + (size_t)bh * 64 * 2048;

    // DMA staging: wave w stages rows w*8..w*8+7 of K and V (1024 B each).
    // LDS dest linear; global source chunk pre-swizzled: chunk ^= row&7.
    const int drow = lane >> 3;             // 0..7 within slice
    const int dchk = (lane & 7) ^ drow;     // pre-swizzled source chunk
    const int grow = w * 8 + drow;          // row 0..63 (grow&7 == drow)

    // Q B-fragments straight from global (one-time): B[k=d][col=qrow]
    s8v bq[4];
    {
        const unsigned short* qrow = qp + (size_t)(qb + l31) * E3_;
        #pragma unroll
        for (int ks = 0; ks < 4; ks++)
            bq[ks] = *(const s8v*)(qrow + ks * 16 + h8);
    }

    // ones B-fragment (bf16 1.0) for row-sum MFMA
    s8v ones;
    #pragma unroll
    for (int i = 0; i < 8; i++) ones[i] = (short)0x3F80;

    const f16v fzero = {0.f,0.f,0.f,0.f,0.f,0.f,0.f,0.f,
                        0.f,0.f,0.f,0.f,0.f,0.f,0.f,0.f};
    f16v o0 = fzero, o1 = fzero;   // d = 0..31 / 32..63
    f16v lc = fzero;               // row-sums, layout-matched to o

    // ---- prologue: DMA tile 0 into buffer 0 ----
    gload_lds16(kp  + (size_t)grow * E3_  + dchk * 8, &Ks[0][w * 8][0]);
    gload_lds16(vtp + (size_t)grow * 2048 + dchk * 8, &Vs[0][w * 8][0]);
    __syncthreads();   // vmcnt(0) drain + barrier

    for (int kt = 0; kt < N_ / 64; kt++) {
        const int cur = kt & 1;

        // ---- DMA next tile into back buffer (latency hidden by compute) ----
        if (kt + 1 < N_ / 64) {
            const int kn = (kt + 1) * 64;
            gload_lds16(kp  + (size_t)(kn + grow) * E3_  + dchk * 8,
                        &Ks[cur ^ 1][w * 8][0]);
            gload_lds16(vtp + (size_t)grow * 2048 + kn + dchk * 8,
                        &Vs[cur ^ 1][w * 8][0]);
        }

        #pragma unroll
        for (int ksub = 0; ksub < 2; ksub++) {
            // K A-fragments: A[row=key][k=d], row = ksub*32 + l31
            const int krow = ksub * 32 + l31;
            const int ksw  = (l31 & 7) * 8;     // krow&7 == l31&7
            s8v ak[4];
            #pragma unroll
            for (int ks = 0; ks < 4; ks++)
                ak[ks] = *(const s8v*)&Ks[cur][krow][(ks * 16 + h8) ^ ksw];

            // S^T -> exp2 -> in-register P A-fragments
            f16v st = fzero;
            __builtin_amdgcn_s_setprio(1);
            st = __builtin_amdgcn_mfma_f32_32x32x16_bf16(ak[0], bq[0], st, 0, 0, 0);
            st = __builtin_amdgcn_mfma_f32_32x32x16_bf16(ak[1], bq[1], st, 0, 0, 0);
            st = __builtin_amdgcn_mfma_f32_32x32x16_bf16(ak[2], bq[2], st, 0, 0, 0);
            st = __builtin_amdgcn_mfma_f32_32x32x16_bf16(ak[3], bq[3], st, 0, 0, 0);
            __builtin_amdgcn_s_setprio(0);

            float pe[16];
            #pragma unroll
            for (int i = 0; i < 16; i++)
                pe[i] = __builtin_amdgcn_exp2f(st[i]);

            // pack pairs, swap halves: lane gets its q-row's keys
            // lo lane -> keys {0..7}(+16j), hi lane -> keys {8..15}(+16j)
            s8v pa[2];
            {
                union { s8v v; unsigned int u[4]; } f0, f1;
                uint2 r;
                r = pl32(cvtpk(pe[0],  pe[1]),  cvtpk(pe[4],  pe[5]));
                f0.u[0] = r.x; f0.u[2] = r.y;
                r = pl32(cvtpk(pe[2],  pe[3]),  cvtpk(pe[6],  pe[7]));
                f0.u[1] = r.x; f0.u[3] = r.y;
                r = pl32(cvtpk(pe[8],  pe[9]),  cvtpk(pe[12], pe[13]));
                f1.u[0] = r.x; f1.u[2] = r.y;
                r = pl32(cvtpk(pe[10], pe[11]), cvtpk(pe[14], pe[15]));
                f1.u[1] = r.x; f1.u[3] = r.y;
                pa[0] = f0.v;   // keys ksub*32 + 0..15
                pa[1] = f1.v;   // keys ksub*32 + 16..31
            }

            // ---- O += P V ; l += P @ ones ----
            #pragma unroll
            for (int j = 0; j < 2; j++) {
                const int kbase = (ksub * 2 + j) * 16 + h8;
                const int vsw   = (l31 & 7) * 8;
                s8v bv0 = *(const s8v*)&Vs[cur][l31     ][kbase ^ vsw];
                s8v bv1 = *(const s8v*)&Vs[cur][32 + l31][kbase ^ vsw];
                __builtin_amdgcn_s_setprio(1);
                o0 = __builtin_amdgcn_mfma_f32_32x32x16_bf16(pa[j], bv0, o0, 0, 0, 0);
                o1 = __builtin_amdgcn_mfma_f32_32x32x16_bf16(pa[j], bv1, o1, 0, 0, 0);
                lc = __builtin_amdgcn_mfma_f32_32x32x16_bf16(pa[j], ones, lc, 0, 0, 0);
                __builtin_amdgcn_s_setprio(0);
            }
        }

        __syncthreads();   // drains DMA vmcnt + all reads of cur complete
    }

    // normalize + write ao bf16 [m][1024]; lc layout == o layout
    {
        float inv[16];
        #pragma unroll
        for (int r = 0; r < 16; r++) inv[r] = 1.f / lc[r];
        #pragma unroll
        for (int r = 0; r < 16; r++) {
            const int qrow = qb + (r & 3) + 8 * (r >> 2) + 4 * hi5;
            const size_t base = ((size_t)b * N_ + qrow) * (H_ * DH_) + h * DH_;
            ao[base + l31]      = f2bf_fast(o0[r] * inv[r]);
            ao[base + 32 + l31] = f2bf_fast(o1[r] * inv[r]);
        }
    }
}

// ---------------------------------------------------------------------------
// Launch
// ---------------------------------------------------------------------------
extern "C" void kernel_launch(void* const* d_in, const int* in_sizes, int n_in,
                              void* d_out, int out_size, void* d_ws, size_t ws_size,
                              hipStream_t stream) {
    const float* x     = (const float*)d_in[0];   // [B,N,DIM]
    const float* w_qkv = (const float*)d_in[1];   // [3072, 1024]
    const float* w_out = (const float*)d_in[2];   // [1024, 1024]
    const float* b_out = (const float*)d_in[3];   // [1024]
    float* out = (float*)d_out;                   // [B,N,DIM] fp32

    char* ws = (char*)d_ws;
    unsigned short* x_bf    = (unsigned short*)(ws);                        // 16 MB
    unsigned short* wqkv_bf = (unsigned short*)(ws + (((size_t)16) << 20)); //  6 MB
    unsigned short* wout_bf = (unsigned short*)(ws + (((size_t)22) << 20)); //  2 MB
    unsigned short* qkv_bf  = (unsigned short*)(ws + (((size_t)24) << 20)); // 48 MB
    unsigned short* vT      = (unsigned short*)(ws + (((size_t)72) << 20)); // 16 MB
    unsigned short* ao_bf   = (unsigned short*)(ws + (((size_t)88) << 20)); // 16 MB

    const int M = B_ * N_;   // 8192

    // 0) input conversions fp32 -> bf16
    cvt_bf16<<<(M * DIM_) / 1024, 256, 0, stream>>>(x, x_bf, M * DIM_);
    cvt_bf16<<<(E3_ * DIM_) / 1024, 256, 0, stream>>>(w_qkv, wqkv_bf, E3_ * DIM_);
    cvt_bf16<<<(DIM_ * DIM_) / 1024, 256, 0, stream>>>(w_out, wout_bf, DIM_ * DIM_);

    // 1) QKV projection (bf16 MFMA): Q pre-scaled, V redirected to vT
    {
        dim3 grid(E3_ / 128, M / 128);   // (24, 64) = 1536 blocks (%8==0)
        gemm_mfma<0><<<grid, 256, 0, stream>>>(x_bf, wqkv_bf, nullptr,
                                               qkv_bf, vT, nullptr, M, E3_, DIM_);
    }
    // 2) attention (32x32 MFMA, in-register P, DMA-staged swizzled K/V,
    //    8 waves x 32 q-rows, 4 waves/SIMD)
    {
        dim3 grid(N_ / 256, B_ * H_);    // (8, 64) = 512 blocks = 2/CU
        attn_mfma<<<grid, 512, 0, stream>>>(qkv_bf, vT, ao_bf);
    }
    // 3) out projection (bf16 MFMA, fp32 + bias out)
    {
        dim3 grid(DIM_ / 128, M / 128);  // (8, 64) = 512 blocks (%8==0)
        gemm_mfma<1><<<grid, 256, 0, stream>>>(ao_bf, wout_bf, b_out,
                                               nullptr, nullptr, out, M, DIM_, DIM_);
    }
    (void)in_sizes; (void)n_in; (void)out_size; (void)ws_size;
}

// Round 4
// 257.743 us; speedup vs baseline: 1.1330x; 1.0722x over previous
//
#include <hip/hip_runtime.h>
#include <hip/hip_bf16.h>
#include <math.h>

// Problem constants
#define B_   4
#define N_   2048
#define DIM_ 1024
#define H_   16
#define DH_  64
#define E3_  3072   // 3*H*DH

typedef __attribute__((ext_vector_type(8)))  short s8v;   // 8 bf16 (4 VGPRs)
typedef __attribute__((ext_vector_type(4)))  float f4v;   // 16x16 MFMA accumulator
typedef __attribute__((ext_vector_type(16))) float f16v;  // 32x32 MFMA accumulator

// fast fp32->bf16: round-half-up (adds 0.5 ulp then truncate). 2 VALU ops.
__device__ __forceinline__ unsigned short f2bf_fast(float f) {
    return (unsigned short)((__builtin_bit_cast(unsigned int, f) + 0x8000u) >> 16);
}
// pack two fp32 -> two bf16 in one u32 via v_perm_b32 (3 VALU ops total)
__device__ __forceinline__ unsigned int pkbf(float a, float b) {
    unsigned int ua = __builtin_bit_cast(unsigned int, a) + 0x8000u;
    unsigned int ub = __builtin_bit_cast(unsigned int, b) + 0x8000u;
    return __builtin_amdgcn_perm(ub, ua, 0x07060302);
}
// single-instruction pack: dst.lo = bf16(a), dst.hi = bf16(b)  (RNE)
__device__ __forceinline__ unsigned int cvtpk(float a, float b) {
    unsigned int r;
    asm("v_cvt_pk_bf16_f32 %0, %1, %2" : "=v"(r) : "v"(a), "v"(b));
    return r;
}
// v_permlane32_swap_b32: after execution
//   a' = [a(lanes 0:31) | b(lanes 0:31)],  b' = [a(lanes 32:63) | b(lanes 32:63)]
__device__ __forceinline__ uint2 pl32(unsigned int a, unsigned int b) {
    asm volatile("v_permlane32_swap_b32 %0, %1" : "+v"(a), "+v"(b));
    return make_uint2(a, b);
}

// async global->LDS, 16 B per lane; LDS dest = wave-uniform base + lane*16
__device__ __forceinline__ void gload_lds16(const void* g, void* l) {
    __builtin_amdgcn_global_load_lds(
        (const __attribute__((address_space(1))) unsigned int*)(uintptr_t)g,
        (__attribute__((address_space(3))) unsigned int*)(uintptr_t)l,
        16, 0, 0);
}

// ---------------------------------------------------------------------------
// fp32 -> bf16 convert (perm-packed)
// ---------------------------------------------------------------------------
__global__ __launch_bounds__(256) void cvt_bf16(
    const float* __restrict__ in, unsigned short* __restrict__ out, int n)
{
    const int i = (blockIdx.x * 256 + threadIdx.x) * 4;
    if (i < n) {
        float4 v = *(const float4*)(in + i);
        uint2 pk;
        pk.x = pkbf(v.x, v.y);
        pk.y = pkbf(v.z, v.w);
        *(uint2*)(out + i) = pk;
    }
}

// ---------------------------------------------------------------------------
// QKV projection GEMM v2: qkv[8192][3072] = x[8192][1024] @ w_qkv^T.
// BM=256 x BN=192 x BK=64, 512 thr = 8 waves (2M x 4N), wave tile 128x48
// (8x3 16x16x32 MFMAs x 2 k-steps = 48 MFMA/iter). Round-3 profile showed
// the 128x128/BK32 version LDS-read-bound (MfmaUtil 27, 8 b128/16 MFMA);
// this tile is 1.6x higher FLOP/LDS-byte (22 b128/48 MFMA).
// - LDS [row][64] XOR-swizzled (chunk ^= row&7) BOTH sides: pre-swizzled
//   global_load_lds source + swizzled ds_read (attn-v7-verified pattern).
// - double-buffered, next tile's 7 gloads/wave issued BEFORE compute ->
//   the barrier's implicit vmcnt(0) drain is ~free (attn-v7 loop shape).
// - grid (16,32) = 512 blocks = exactly 2 rounds on 256 CUs (no tail).
// - XCD-chunked swizzle: 4 consecutive A-panels (and their 16 N-blocks)
//   per XCD -> A reads L2-resident.
// Q-third pre-scaled by 0.125*log2(e); V-third redirected to vT[b,h,d,n].
// ---------------------------------------------------------------------------
__global__ __launch_bounds__(512, 1) void gemm_qkv(
    const unsigned short* __restrict__ A,    // x_bf [8192][1024]
    const unsigned short* __restrict__ Bw,   // wqkv_bf [3072][1024]
    unsigned short* __restrict__ Cb,         // qkv bf16 [8192][3072]
    unsigned short* __restrict__ Vt)         // [B*H][64][2048]
{
    // [buf][(256 A-rows + 192 B-rows) * 64 el]; 112 KB total
    __shared__ unsigned short Ls[2][28672];

    const int tid  = threadIdx.x;
    const int w    = tid >> 6;          // 0..7
    const int lane = tid & 63;
    const int quad = lane >> 4;
    const int l15  = lane & 15;
    const int wm   = w & 1;             // M half (128 rows)
    const int wn   = w >> 1;            // N quarter (48 cols)

    // XCD-chunked swizzle: 512 blocks -> 64 per XCD (4 full A-panel rows)
    const int lin = blockIdx.y * 16 + blockIdx.x;
    const int swz = (lin & 7) * 64 + (lin >> 3);
    const int m0  = (swz >> 4) * 256;
    const int n0  = (swz & 15) * 192;

    // staging: 56 units of 1 KB (8 rows x 64 el); wave w stages units
    // w*7..w*7+6. Lane: row = unit*8 + (lane>>3), source chunk pre-swizzled.
    const int r8  = lane >> 3;              // 0..7
    const int chk = (lane & 7) ^ r8;        // pre-swizzled source chunk

    f4v acc[8][3];
    #pragma unroll
    for (int i = 0; i < 8; i++)
        #pragma unroll
        for (int j = 0; j < 3; j++) acc[i][j] = (f4v){0.f, 0.f, 0.f, 0.f};

    // ---- prologue: stage tile 0 into buffer 0 ----
    #pragma unroll
    for (int j = 0; j < 7; j++) {
        const int u = w * 7 + j;
        const unsigned short* src = (u < 32)
            ? A  + (size_t)(m0 + u * 8 + r8) * 1024 + chk * 8
            : Bw + (size_t)(n0 + (u - 32) * 8 + r8) * 1024 + chk * 8;
        gload_lds16(src, &Ls[0][u * 512]);
    }
    __syncthreads();

    for (int t = 0; t < 16; t++) {
        const int cur = t & 1;

        // ---- issue next tile's DMA first (latency hidden by compute) ----
        if (t + 1 < 16) {
            const int k0 = (t + 1) * 64;
            #pragma unroll
            for (int j = 0; j < 7; j++) {
                const int u = w * 7 + j;
                const unsigned short* src = (u < 32)
                    ? A  + (size_t)(m0 + u * 8 + r8) * 1024 + k0 + chk * 8
                    : Bw + (size_t)(n0 + (u - 32) * 8 + r8) * 1024 + k0 + chk * 8;
                gload_lds16(src, &Ls[cur ^ 1][u * 512]);
            }
        }

        // ---- compute on current buffer: 2 k-steps x (8x3) MFMAs ----
        #pragma unroll
        for (int s = 0; s < 2; s++) {
            s8v af[8], bf[3];
            #pragma unroll
            for (int ms = 0; ms < 8; ms++) {
                const int row = wm * 128 + ms * 16 + l15;
                af[ms] = *(const s8v*)&Ls[cur][row * 64 + (((s * 4 + quad) ^ (l15 & 7)) * 8)];
            }
            #pragma unroll
            for (int ns = 0; ns < 3; ns++) {
                const int row = 256 + wn * 48 + ns * 16 + l15;
                bf[ns] = *(const s8v*)&Ls[cur][row * 64 + (((s * 4 + quad) ^ (l15 & 7)) * 8)];
            }
            __builtin_amdgcn_s_setprio(1);
            #pragma unroll
            for (int ms = 0; ms < 8; ms++)
                #pragma unroll
                for (int ns = 0; ns < 3; ns++)
                    acc[ms][ns] = __builtin_amdgcn_mfma_f32_16x16x32_bf16(
                        af[ms], bf[ns], acc[ms][ns], 0, 0, 0);
            __builtin_amdgcn_s_setprio(0);
        }

        __syncthreads();   // reads of cur done; next tile's DMA drained
    }

    // ---- epilogue: C/D layout col = l15, row = quad*4 + r ----
    #pragma unroll
    for (int ns = 0; ns < 3; ns++) {
        const int colb = n0 + wn * 48 + ns * 16;   // wave-uniform, 16-aligned
        if (colb < 2048) {
            // fold softmax scale*log2(e) into Q columns
            const float mul = (colb < 1024) ? 0.18033688011112042f : 1.0f;
            #pragma unroll
            for (int ms = 0; ms < 8; ms++)
                #pragma unroll
                for (int r = 0; r < 4; r++) {
                    const int row = m0 + wm * 128 + ms * 16 + quad * 4 + r;
                    Cb[(size_t)row * E3_ + colb + l15] = f2bf_fast(acc[ms][ns][r] * mul);
                }
        } else {
            const int e = colb + l15 - 2048;
            const int hh = e >> 6, d = e & 63;       // wave-uniform head
            #pragma unroll
            for (int ms = 0; ms < 8; ms++) {
                const int row = m0 + wm * 128 + ms * 16 + quad * 4;  // 4-aligned
                const int bb = row >> 11, nn = row & 2047;
                uint2 pk;
                pk.x = pkbf(acc[ms][ns][0], acc[ms][ns][1]);
                pk.y = pkbf(acc[ms][ns][2], acc[ms][ns][3]);
                *(uint2*)&Vt[(((size_t)bb * 16 + hh) * 64 + d) * 2048 + nn] = pk;
            }
        }
    }
}

// ---------------------------------------------------------------------------
// bf16 MFMA GEMM, m97 structure (kept for the out-projection only):
// C[M,Nc] = A[M,K] @ Bw[Nc,K]^T, fp32 + bias out.
// 128x128 tile, BK=32, 256 thr = 4 waves (2x2), each wave 64x64 via 4x4
// 16x16x32 MFMAs. global_load_lds width 16, no LDS padding (required).
// XCD-chunked block swizzle (T1): nwg%8==0.
// ---------------------------------------------------------------------------
__global__ __launch_bounds__(256) void gemm_out(
    const unsigned short* __restrict__ A,
    const unsigned short* __restrict__ Bw,
    const float* __restrict__ bias,
    float* __restrict__ Cf,
    int M, int Nc, int K)
{
    __shared__ unsigned short As[128 * 32];
    __shared__ unsigned short Bs[128 * 32];

    const int tid  = threadIdx.x;
    const int w    = tid >> 6;
    const int lane = tid & 63;
    const int quad = lane >> 4;
    const int l15  = lane & 15;
    const int wm   = w & 1, wn = w >> 1;

    const int nwx = gridDim.x;
    const int lin = blockIdx.y * nwx + blockIdx.x;
    const int cpx = (nwx * gridDim.y) >> 3;       // nwg/8 (nwg%8==0)
    const int swz = (lin & 7) * cpx + (lin >> 3);
    const int m0  = (swz / nwx) * 128, n0 = (swz % nwx) * 128;

    const int srow = lane >> 2;        // 0..15
    const int sch  = (lane & 3) * 8;   // k element offset 0,8,16,24

    f4v acc[4][4];
    #pragma unroll
    for (int i = 0; i < 4; i++)
        #pragma unroll
        for (int j = 0; j < 4; j++) acc[i][j] = (f4v){0.f, 0.f, 0.f, 0.f};

    for (int k0 = 0; k0 < K; k0 += 32) {
        __syncthreads();   // fragment reads of prev iter complete
        #pragma unroll
        for (int i = 0; i < 2; i++) {
            const int rbase = w * 32 + i * 16;   // 16 rows per instruction
            gload_lds16(A  + (size_t)(m0 + rbase + srow) * K + k0 + sch,
                        &As[rbase * 32]);
            gload_lds16(Bw + (size_t)(n0 + rbase + srow) * K + k0 + sch,
                        &Bs[rbase * 32]);
        }
        __syncthreads();   // drains vmcnt -> LDS visible

        s8v af[4], bf[4];
        #pragma unroll
        for (int i = 0; i < 4; i++) {
            af[i] = *(const s8v*)&As[(wm * 64 + i * 16 + l15) * 32 + quad * 8];
            bf[i] = *(const s8v*)&Bs[(wn * 64 + i * 16 + l15) * 32 + quad * 8];
        }
        #pragma unroll
        for (int ms = 0; ms < 4; ms++)
            #pragma unroll
            for (int ns = 0; ns < 4; ns++)
                acc[ms][ns] = __builtin_amdgcn_mfma_f32_16x16x32_bf16(
                    af[ms], bf[ns], acc[ms][ns], 0, 0, 0);
    }

    #pragma unroll
    for (int ns = 0; ns < 4; ns++) {
        const float bz = bias[n0 + wn * 64 + ns * 16 + l15];
        #pragma unroll
        for (int ms = 0; ms < 4; ms++)
            #pragma unroll
            for (int r = 0; r < 4; r++) {
                const int row = m0 + wm * 64 + ms * 16 + quad * 4 + r;
                Cf[(size_t)row * Nc + n0 + wn * 64 + ns * 16 + l15] =
                    acc[ms][ns][r] + bz;
            }
    }
}

// ---------------------------------------------------------------------------
// MFMA flash attention v7: 32x32x16, in-register P, 8 waves x 32 q-rows.
// (unchanged from round 3 — see comments there)
// ---------------------------------------------------------------------------
__global__ __launch_bounds__(512, 4) void attn_mfma(
    const unsigned short* __restrict__ qkv,
    const unsigned short* __restrict__ vT,
    unsigned short* __restrict__ ao)
{
    __shared__ __align__(16) unsigned short Ks[2][64][64];   // [buf][key][d] swz
    __shared__ __align__(16) unsigned short Vs[2][64][64];   // [buf][d][key] swz

    const int tid  = threadIdx.x;
    const int w    = tid >> 6;          // 0..7
    const int lane = tid & 63;
    const int l31  = lane & 31;
    const int hi5  = lane >> 5;         // 0/1
    const int h8   = hi5 * 8;

    const int lin = blockIdx.y * 8 + blockIdx.x;
    const int swz = (lin & 7) * 64 + (lin >> 3);
    const int bx  = swz & 7;
    const int bh  = swz >> 3;
    const int b   = bh >> 4;
    const int h   = bh & 15;
    const int q0  = bx * 256;           // 256 q-rows per block
    const int qb  = q0 + w * 32;        // 32 q-rows per wave

    const unsigned short* qp  = qkv + (size_t)b * N_ * E3_ + (size_t)h * DH_;
    const unsigned short* kp  = qp + 1024;
    const unsigned short* vtp = vT + (size_t)bh * 64 * 2048;

    const int drow = lane >> 3;             // 0..7 within slice
    const int dchk = (lane & 7) ^ drow;     // pre-swizzled source chunk
    const int grow = w * 8 + drow;          // row 0..63 (grow&7 == drow)

    s8v bq[4];
    {
        const unsigned short* qrow = qp + (size_t)(qb + l31) * E3_;
        #pragma unroll
        for (int ks = 0; ks < 4; ks++)
            bq[ks] = *(const s8v*)(qrow + ks * 16 + h8);
    }

    s8v ones;
    #pragma unroll
    for (int i = 0; i < 8; i++) ones[i] = (short)0x3F80;

    const f16v fzero = {0.f,0.f,0.f,0.f,0.f,0.f,0.f,0.f,
                        0.f,0.f,0.f,0.f,0.f,0.f,0.f,0.f};
    f16v o0 = fzero, o1 = fzero;   // d = 0..31 / 32..63
    f16v lc = fzero;               // row-sums, layout-matched to o

    gload_lds16(kp  + (size_t)grow * E3_  + dchk * 8, &Ks[0][w * 8][0]);
    gload_lds16(vtp + (size_t)grow * 2048 + dchk * 8, &Vs[0][w * 8][0]);
    __syncthreads();

    for (int kt = 0; kt < N_ / 64; kt++) {
        const int cur = kt & 1;

        if (kt + 1 < N_ / 64) {
            const int kn = (kt + 1) * 64;
            gload_lds16(kp  + (size_t)(kn + grow) * E3_  + dchk * 8,
                        &Ks[cur ^ 1][w * 8][0]);
            gload_lds16(vtp + (size_t)grow * 2048 + kn + dchk * 8,
                        &Vs[cur ^ 1][w * 8][0]);
        }

        #pragma unroll
        for (int ksub = 0; ksub < 2; ksub++) {
            const int krow = ksub * 32 + l31;
            const int ksw  = (l31 & 7) * 8;     // krow&7 == l31&7
            s8v ak[4];
            #pragma unroll
            for (int ks = 0; ks < 4; ks++)
                ak[ks] = *(const s8v*)&Ks[cur][krow][(ks * 16 + h8) ^ ksw];

            f16v st = fzero;
            __builtin_amdgcn_s_setprio(1);
            st = __builtin_amdgcn_mfma_f32_32x32x16_bf16(ak[0], bq[0], st, 0, 0, 0);
            st = __builtin_amdgcn_mfma_f32_32x32x16_bf16(ak[1], bq[1], st, 0, 0, 0);
            st = __builtin_amdgcn_mfma_f32_32x32x16_bf16(ak[2], bq[2], st, 0, 0, 0);
            st = __builtin_amdgcn_mfma_f32_32x32x16_bf16(ak[3], bq[3], st, 0, 0, 0);
            __builtin_amdgcn_s_setprio(0);

            float pe[16];
            #pragma unroll
            for (int i = 0; i < 16; i++)
                pe[i] = __builtin_amdgcn_exp2f(st[i]);

            s8v pa[2];
            {
                union { s8v v; unsigned int u[4]; } f0, f1;
                uint2 r;
                r = pl32(cvtpk(pe[0],  pe[1]),  cvtpk(pe[4],  pe[5]));
                f0.u[0] = r.x; f0.u[2] = r.y;
                r = pl32(cvtpk(pe[2],  pe[3]),  cvtpk(pe[6],  pe[7]));
                f0.u[1] = r.x; f0.u[3] = r.y;
                r = pl32(cvtpk(pe[8],  pe[9]),  cvtpk(pe[12], pe[13]));
                f1.u[0] = r.x; f1.u[2] = r.y;
                r = pl32(cvtpk(pe[10], pe[11]), cvtpk(pe[14], pe[15]));
                f1.u[1] = r.x; f1.u[3] = r.y;
                pa[0] = f0.v;   // keys ksub*32 + 0..15
                pa[1] = f1.v;   // keys ksub*32 + 16..31
            }

            #pragma unroll
            for (int j = 0; j < 2; j++) {
                const int kbase = (ksub * 2 + j) * 16 + h8;
                const int vsw   = (l31 & 7) * 8;
                s8v bv0 = *(const s8v*)&Vs[cur][l31     ][kbase ^ vsw];
                s8v bv1 = *(const s8v*)&Vs[cur][32 + l31][kbase ^ vsw];
                __builtin_amdgcn_s_setprio(1);
                o0 = __builtin_amdgcn_mfma_f32_32x32x16_bf16(pa[j], bv0, o0, 0, 0, 0);
                o1 = __builtin_amdgcn_mfma_f32_32x32x16_bf16(pa[j], bv1, o1, 0, 0, 0);
                lc = __builtin_amdgcn_mfma_f32_32x32x16_bf16(pa[j], ones, lc, 0, 0, 0);
                __builtin_amdgcn_s_setprio(0);
            }
        }

        __syncthreads();
    }

    {
        float inv[16];
        #pragma unroll
        for (int r = 0; r < 16; r++) inv[r] = 1.f / lc[r];
        #pragma unroll
        for (int r = 0; r < 16; r++) {
            const int qrow = qb + (r & 3) + 8 * (r >> 2) + 4 * hi5;
            const size_t base = ((size_t)b * N_ + qrow) * (H_ * DH_) + h * DH_;
            ao[base + l31]      = f2bf_fast(o0[r] * inv[r]);
            ao[base + 32 + l31] = f2bf_fast(o1[r] * inv[r]);
        }
    }
}

// ---------------------------------------------------------------------------
// Launch
// ---------------------------------------------------------------------------
extern "C" void kernel_launch(void* const* d_in, const int* in_sizes, int n_in,
                              void* d_out, int out_size, void* d_ws, size_t ws_size,
                              hipStream_t stream) {
    const float* x     = (const float*)d_in[0];   // [B,N,DIM]
    const float* w_qkv = (const float*)d_in[1];   // [3072, 1024]
    const float* w_out = (const float*)d_in[2];   // [1024, 1024]
    const float* b_out = (const float*)d_in[3];   // [1024]
    float* out = (float*)d_out;                   // [B,N,DIM] fp32

    char* ws = (char*)d_ws;
    unsigned short* x_bf    = (unsigned short*)(ws);                        // 16 MB
    unsigned short* wqkv_bf = (unsigned short*)(ws + (((size_t)16) << 20)); //  6 MB
    unsigned short* wout_bf = (unsigned short*)(ws + (((size_t)22) << 20)); //  2 MB
    unsigned short* qkv_bf  = (unsigned short*)(ws + (((size_t)24) << 20)); // 48 MB
    unsigned short* vT      = (unsigned short*)(ws + (((size_t)72) << 20)); // 16 MB
    unsigned short* ao_bf   = (unsigned short*)(ws + (((size_t)88) << 20)); // 16 MB

    const int M = B_ * N_;   // 8192

    // 0) input conversions fp32 -> bf16
    cvt_bf16<<<(M * DIM_) / 1024, 256, 0, stream>>>(x, x_bf, M * DIM_);
    cvt_bf16<<<(E3_ * DIM_) / 1024, 256, 0, stream>>>(w_qkv, wqkv_bf, E3_ * DIM_);
    cvt_bf16<<<(DIM_ * DIM_) / 1024, 256, 0, stream>>>(w_out, wout_bf, DIM_ * DIM_);

    // 1) QKV projection v2: 256x192x64 tiles, dbuf+prefetch, swizzled LDS
    {
        dim3 grid(E3_ / 192, M / 256);   // (16, 32) = 512 blocks = 2 rounds
        gemm_qkv<<<grid, 512, 0, stream>>>(x_bf, wqkv_bf, qkv_bf, vT);
    }
    // 2) attention (32x32 MFMA, in-register P, DMA-staged swizzled K/V,
    //    8 waves x 32 q-rows, 4 waves/SIMD)
    {
        dim3 grid(N_ / 256, B_ * H_);    // (8, 64) = 512 blocks = 2/CU
        attn_mfma<<<grid, 512, 0, stream>>>(qkv_bf, vT, ao_bf);
    }
    // 3) out projection (bf16 MFMA, fp32 + bias out)
    {
        dim3 grid(DIM_ / 128, M / 128);  // (8, 64) = 512 blocks (%8==0)
        gemm_out<<<grid, 256, 0, stream>>>(ao_bf, wout_bf, b_out,
                                           out, M, DIM_, DIM_);
    }
    (void)in_sizes; (void)n_in; (void)out_size; (void)ws_size;
}

// Round 6
// 254.267 us; speedup vs baseline: 1.1485x; 1.0137x over previous
//
#include <hip/hip_runtime.h>
#include <hip/hip_bf16.h>
#include <math.h>

// Problem constants
#define B_   4
#define N_   2048
#define DIM_ 1024
#define H_   16
#define DH_  64
#define E3_  3072   // 3*H*DH

typedef __attribute__((ext_vector_type(8)))  short s8v;   // 8 bf16 (4 VGPRs)
typedef __attribute__((ext_vector_type(4)))  float f4v;   // 16x16 MFMA accumulator
typedef __attribute__((ext_vector_type(16))) float f16v;  // 32x32 MFMA accumulator

// fast fp32->bf16: round-half-up (adds 0.5 ulp then truncate). 2 VALU ops.
__device__ __forceinline__ unsigned short f2bf_fast(float f) {
    return (unsigned short)((__builtin_bit_cast(unsigned int, f) + 0x8000u) >> 16);
}
// pack two fp32 -> two bf16 in one u32 via v_perm_b32 (3 VALU ops total)
__device__ __forceinline__ unsigned int pkbf(float a, float b) {
    unsigned int ua = __builtin_bit_cast(unsigned int, a) + 0x8000u;
    unsigned int ub = __builtin_bit_cast(unsigned int, b) + 0x8000u;
    return __builtin_amdgcn_perm(ub, ua, 0x07060302);
}
// single-instruction pack: dst.lo = bf16(a), dst.hi = bf16(b)  (RNE)
__device__ __forceinline__ unsigned int cvtpk(float a, float b) {
    unsigned int r;
    asm("v_cvt_pk_bf16_f32 %0, %1, %2" : "=v"(r) : "v"(a), "v"(b));
    return r;
}
// v_permlane32_swap_b32: after execution
//   a' = [a(lanes 0:31) | b(lanes 0:31)],  b' = [a(lanes 32:63) | b(lanes 32:63)]
__device__ __forceinline__ uint2 pl32(unsigned int a, unsigned int b) {
    asm volatile("v_permlane32_swap_b32 %0, %1" : "+v"(a), "+v"(b));
    return make_uint2(a, b);
}

// async global->LDS, 16 B per lane; LDS dest = wave-uniform base + lane*16
__device__ __forceinline__ void gload_lds16(const void* g, void* l) {
    __builtin_amdgcn_global_load_lds(
        (const __attribute__((address_space(1))) unsigned int*)(uintptr_t)g,
        (__attribute__((address_space(3))) unsigned int*)(uintptr_t)l,
        16, 0, 0);
}

// ---------------------------------------------------------------------------
// fp32 -> bf16 convert (perm-packed)
// ---------------------------------------------------------------------------
__global__ __launch_bounds__(256) void cvt_bf16(
    const float* __restrict__ in, unsigned short* __restrict__ out, int n)
{
    const int i = (blockIdx.x * 256 + threadIdx.x) * 4;
    if (i < n) {
        float4 v = *(const float4*)(in + i);
        uint2 pk;
        pk.x = pkbf(v.x, v.y);
        pk.y = pkbf(v.z, v.w);
        *(uint2*)(out + i) = pk;
    }
}

// ---------------------------------------------------------------------------
// QKV projection GEMM v2 (unchanged from round 4; see comments there)
// ---------------------------------------------------------------------------
__global__ __launch_bounds__(512, 1) void gemm_qkv(
    const unsigned short* __restrict__ A,    // x_bf [8192][1024]
    const unsigned short* __restrict__ Bw,   // wqkv_bf [3072][1024]
    unsigned short* __restrict__ Cb,         // qkv bf16 [8192][3072]
    unsigned short* __restrict__ Vt)         // [B*H][64][2048]
{
    __shared__ unsigned short Ls[2][28672];

    const int tid  = threadIdx.x;
    const int w    = tid >> 6;          // 0..7
    const int lane = tid & 63;
    const int quad = lane >> 4;
    const int l15  = lane & 15;
    const int wm   = w & 1;             // M half (128 rows)
    const int wn   = w >> 1;            // N quarter (48 cols)

    const int lin = blockIdx.y * 16 + blockIdx.x;
    const int swz = (lin & 7) * 64 + (lin >> 3);
    const int m0  = (swz >> 4) * 256;
    const int n0  = (swz & 15) * 192;

    const int r8  = lane >> 3;              // 0..7
    const int chk = (lane & 7) ^ r8;        // pre-swizzled source chunk

    f4v acc[8][3];
    #pragma unroll
    for (int i = 0; i < 8; i++)
        #pragma unroll
        for (int j = 0; j < 3; j++) acc[i][j] = (f4v){0.f, 0.f, 0.f, 0.f};

    #pragma unroll
    for (int j = 0; j < 7; j++) {
        const int u = w * 7 + j;
        const unsigned short* src = (u < 32)
            ? A  + (size_t)(m0 + u * 8 + r8) * 1024 + chk * 8
            : Bw + (size_t)(n0 + (u - 32) * 8 + r8) * 1024 + chk * 8;
        gload_lds16(src, &Ls[0][u * 512]);
    }
    __syncthreads();

    for (int t = 0; t < 16; t++) {
        const int cur = t & 1;

        if (t + 1 < 16) {
            const int k0 = (t + 1) * 64;
            #pragma unroll
            for (int j = 0; j < 7; j++) {
                const int u = w * 7 + j;
                const unsigned short* src = (u < 32)
                    ? A  + (size_t)(m0 + u * 8 + r8) * 1024 + k0 + chk * 8
                    : Bw + (size_t)(n0 + (u - 32) * 8 + r8) * 1024 + k0 + chk * 8;
                gload_lds16(src, &Ls[cur ^ 1][u * 512]);
            }
        }

        #pragma unroll
        for (int s = 0; s < 2; s++) {
            s8v af[8], bf[3];
            #pragma unroll
            for (int ms = 0; ms < 8; ms++) {
                const int row = wm * 128 + ms * 16 + l15;
                af[ms] = *(const s8v*)&Ls[cur][row * 64 + (((s * 4 + quad) ^ (l15 & 7)) * 8)];
            }
            #pragma unroll
            for (int ns = 0; ns < 3; ns++) {
                const int row = 256 + wn * 48 + ns * 16 + l15;
                bf[ns] = *(const s8v*)&Ls[cur][row * 64 + (((s * 4 + quad) ^ (l15 & 7)) * 8)];
            }
            __builtin_amdgcn_s_setprio(1);
            #pragma unroll
            for (int ms = 0; ms < 8; ms++)
                #pragma unroll
                for (int ns = 0; ns < 3; ns++)
                    acc[ms][ns] = __builtin_amdgcn_mfma_f32_16x16x32_bf16(
                        af[ms], bf[ns], acc[ms][ns], 0, 0, 0);
            __builtin_amdgcn_s_setprio(0);
        }

        __syncthreads();
    }

    #pragma unroll
    for (int ns = 0; ns < 3; ns++) {
        const int colb = n0 + wn * 48 + ns * 16;   // wave-uniform, 16-aligned
        if (colb < 2048) {
            const float mul = (colb < 1024) ? 0.18033688011112042f : 1.0f;
            #pragma unroll
            for (int ms = 0; ms < 8; ms++)
                #pragma unroll
                for (int r = 0; r < 4; r++) {
                    const int row = m0 + wm * 128 + ms * 16 + quad * 4 + r;
                    Cb[(size_t)row * E3_ + colb + l15] = f2bf_fast(acc[ms][ns][r] * mul);
                }
        } else {
            const int e = colb + l15 - 2048;
            const int hh = e >> 6, d = e & 63;       // wave-uniform head
            #pragma unroll
            for (int ms = 0; ms < 8; ms++) {
                const int row = m0 + wm * 128 + ms * 16 + quad * 4;  // 4-aligned
                const int bb = row >> 11, nn = row & 2047;
                uint2 pk;
                pk.x = pkbf(acc[ms][ns][0], acc[ms][ns][1]);
                pk.y = pkbf(acc[ms][ns][2], acc[ms][ns][3]);
                *(uint2*)&Vt[(((size_t)bb * 16 + hh) * 64 + d) * 2048 + nn] = pk;
            }
        }
    }
}

// ---------------------------------------------------------------------------
// out projection GEMM (unchanged from round 4)
// ---------------------------------------------------------------------------
__global__ __launch_bounds__(256) void gemm_out(
    const unsigned short* __restrict__ A,
    const unsigned short* __restrict__ Bw,
    const float* __restrict__ bias,
    float* __restrict__ Cf,
    int M, int Nc, int K)
{
    __shared__ unsigned short As[128 * 32];
    __shared__ unsigned short Bs[128 * 32];

    const int tid  = threadIdx.x;
    const int w    = tid >> 6;
    const int lane = tid & 63;
    const int quad = lane >> 4;
    const int l15  = lane & 15;
    const int wm   = w & 1, wn = w >> 1;

    const int nwx = gridDim.x;
    const int lin = blockIdx.y * nwx + blockIdx.x;
    const int cpx = (nwx * gridDim.y) >> 3;       // nwg/8 (nwg%8==0)
    const int swz = (lin & 7) * cpx + (lin >> 3);
    const int m0  = (swz / nwx) * 128, n0 = (swz % nwx) * 128;

    const int srow = lane >> 2;        // 0..15
    const int sch  = (lane & 3) * 8;   // k element offset 0,8,16,24

    f4v acc[4][4];
    #pragma unroll
    for (int i = 0; i < 4; i++)
        #pragma unroll
        for (int j = 0; j < 4; j++) acc[i][j] = (f4v){0.f, 0.f, 0.f, 0.f};

    for (int k0 = 0; k0 < K; k0 += 32) {
        __syncthreads();
        #pragma unroll
        for (int i = 0; i < 2; i++) {
            const int rbase = w * 32 + i * 16;
            gload_lds16(A  + (size_t)(m0 + rbase + srow) * K + k0 + sch,
                        &As[rbase * 32]);
            gload_lds16(Bw + (size_t)(n0 + rbase + srow) * K + k0 + sch,
                        &Bs[rbase * 32]);
        }
        __syncthreads();

        s8v af[4], bf[4];
        #pragma unroll
        for (int i = 0; i < 4; i++) {
            af[i] = *(const s8v*)&As[(wm * 64 + i * 16 + l15) * 32 + quad * 8];
            bf[i] = *(const s8v*)&Bs[(wn * 64 + i * 16 + l15) * 32 + quad * 8];
        }
        #pragma unroll
        for (int ms = 0; ms < 4; ms++)
            #pragma unroll
            for (int ns = 0; ns < 4; ns++)
                acc[ms][ns] = __builtin_amdgcn_mfma_f32_16x16x32_bf16(
                    af[ms], bf[ns], acc[ms][ns], 0, 0, 0);
    }

    #pragma unroll
    for (int ns = 0; ns < 4; ns++) {
        const float bz = bias[n0 + wn * 64 + ns * 16 + l15];
        #pragma unroll
        for (int ms = 0; ms < 4; ms++)
            #pragma unroll
            for (int r = 0; r < 4; r++) {
                const int row = m0 + wm * 64 + ms * 16 + quad * 4 + r;
                Cf[(size_t)row * Nc + n0 + wn * 64 + ns * 16 + l15] =
                    acc[ms][ns][r] + bz;
            }
    }
}

// ---------------------------------------------------------------------------
// MFMA flash attention v9: 8 waves x 64 q-rows, lc-MFMA denominator.
// v8 (VALU denominator + permlane fold + LDS-overlay redistribute) FAILED
// with a run-varying error signature (2.3e-2 / 468) -> race or miscompile
// in the only never-proven component; it is QUARANTINED. v9 recombines
// exclusively proven pieces:
// - v8/v6 structure: 512 thr, 8 waves x 64 q (2 subtiles share ak/bv LDS
//   reads -> LDS volume per q halved vs v7), grid (4,64) = 1 block/CU.
// - v7 DMA staging: global_load_lds, linear LDS dest, pre-swizzled source
//   (chunk ^= row&7), double-buffered, one barrier per tile.
// - v6 denominator: lc[sub] = P·ones MFMA, C-layout matches O ->
//   per-lane inv, zero cross-lane redistribution (no LDS overlay).
// MFMA/tile/wave: 40 for 64 q (v7: 40 for 32 q).
// qkv bf16 [m][3072] (Q pre-scaled by 0.125*log2e); vT[b*16+h][d][n] bf16.
// ---------------------------------------------------------------------------
__global__ __launch_bounds__(512, 2) void attn_mfma(
    const unsigned short* __restrict__ qkv,
    const unsigned short* __restrict__ vT,
    unsigned short* __restrict__ ao)
{
    __shared__ __align__(16) unsigned short Ks[2][64][64];   // [buf][key][d] swz
    __shared__ __align__(16) unsigned short Vs[2][64][64];   // [buf][d][key] swz

    const int tid  = threadIdx.x;
    const int w    = tid >> 6;          // 0..7
    const int lane = tid & 63;
    const int l31  = lane & 31;
    const int hi5  = lane >> 5;         // 0/1
    const int h8   = hi5 * 8;

    // XCD mapping: 256 blocks; 8 consecutive bh (32 blocks) per XCD
    const int lin = blockIdx.y * 4 + blockIdx.x;
    const int j0  = (lin & 7) * 32 + (lin >> 3);
    const int bx  = j0 & 3;
    const int bh  = j0 >> 2;
    const int b   = bh >> 4;
    const int h   = bh & 15;
    const int qb  = bx * 512 + w * 64;  // 64 q-rows per wave

    const unsigned short* qp  = qkv + (size_t)b * N_ * E3_ + (size_t)h * DH_;
    const unsigned short* kp  = qp + 1024;
    const unsigned short* vtp = vT + (size_t)bh * 64 * 2048;

    // DMA staging: wave w stages rows w*8..w*8+7 of K and V (1024 B each).
    // LDS dest linear; global source chunk pre-swizzled: chunk ^= row&7.
    const int drow = lane >> 3;             // 0..7 within slice
    const int dchk = (lane & 7) ^ drow;     // pre-swizzled source chunk
    const int grow = w * 8 + drow;          // row 0..63 (grow&7 == drow)

    // Q B-fragments straight from global (one-time): B[k=d][col=qrow]
    s8v bq[2][4];
    #pragma unroll
    for (int sub = 0; sub < 2; sub++) {
        const unsigned short* qrow = qp + (size_t)(qb + sub * 32 + l31) * E3_;
        #pragma unroll
        for (int ks = 0; ks < 4; ks++)
            bq[sub][ks] = *(const s8v*)(qrow + ks * 16 + h8);
    }

    // ones B-fragment (bf16 1.0) for row-sum MFMA
    s8v ones;
    #pragma unroll
    for (int i = 0; i < 8; i++) ones[i] = (short)0x3F80;

    const f16v fzero = {0.f,0.f,0.f,0.f,0.f,0.f,0.f,0.f,
                        0.f,0.f,0.f,0.f,0.f,0.f,0.f,0.f};
    f16v o[2][2];      // [q-subtile][d-tile]
    o[0][0] = fzero; o[0][1] = fzero; o[1][0] = fzero; o[1][1] = fzero;
    f16v lc[2];        // row-sums, layout-matched to o
    lc[0] = fzero; lc[1] = fzero;

    // ---- prologue: DMA tile 0 into buffer 0 ----
    gload_lds16(kp  + (size_t)grow * E3_  + dchk * 8, &Ks[0][w * 8][0]);
    gload_lds16(vtp + (size_t)grow * 2048 + dchk * 8, &Vs[0][w * 8][0]);
    __syncthreads();

    for (int kt = 0; kt < N_ / 64; kt++) {
        const int cur = kt & 1;

        // ---- DMA next tile into back buffer (latency hidden by compute) ----
        if (kt + 1 < N_ / 64) {
            const int kn = (kt + 1) * 64;
            gload_lds16(kp  + (size_t)(kn + grow) * E3_  + dchk * 8,
                        &Ks[cur ^ 1][w * 8][0]);
            gload_lds16(vtp + (size_t)grow * 2048 + kn + dchk * 8,
                        &Vs[cur ^ 1][w * 8][0]);
        }

        #pragma unroll
        for (int ksub = 0; ksub < 2; ksub++) {
            // K A-fragments: A[row=key][k=d], row = ksub*32 + l31 (shared by subs)
            const int krow = ksub * 32 + l31;
            const int ksw  = (l31 & 7) * 8;     // krow&7 == l31&7
            s8v ak[4];
            #pragma unroll
            for (int ks = 0; ks < 4; ks++)
                ak[ks] = *(const s8v*)&Ks[cur][krow][(ks * 16 + h8) ^ ksw];

            // S^T -> exp2 -> in-register P A-fragments, for both q-subtiles
            s8v pa[2][2];   // [sub][j]
            #pragma unroll
            for (int sub = 0; sub < 2; sub++) {
                f16v st = fzero;
                __builtin_amdgcn_s_setprio(1);
                st = __builtin_amdgcn_mfma_f32_32x32x16_bf16(ak[0], bq[sub][0], st, 0, 0, 0);
                st = __builtin_amdgcn_mfma_f32_32x32x16_bf16(ak[1], bq[sub][1], st, 0, 0, 0);
                st = __builtin_amdgcn_mfma_f32_32x32x16_bf16(ak[2], bq[sub][2], st, 0, 0, 0);
                st = __builtin_amdgcn_mfma_f32_32x32x16_bf16(ak[3], bq[sub][3], st, 0, 0, 0);
                __builtin_amdgcn_s_setprio(0);

                float pe[16];
                #pragma unroll
                for (int i = 0; i < 16; i++)
                    pe[i] = __builtin_amdgcn_exp2f(st[i]);

                // pack pairs, swap halves: lane gets its q-row's keys
                union { s8v v; unsigned int u[4]; } f0, f1;
                uint2 r;
                r = pl32(cvtpk(pe[0],  pe[1]),  cvtpk(pe[4],  pe[5]));
                f0.u[0] = r.x; f0.u[2] = r.y;
                r = pl32(cvtpk(pe[2],  pe[3]),  cvtpk(pe[6],  pe[7]));
                f0.u[1] = r.x; f0.u[3] = r.y;
                r = pl32(cvtpk(pe[8],  pe[9]),  cvtpk(pe[12], pe[13]));
                f1.u[0] = r.x; f1.u[2] = r.y;
                r = pl32(cvtpk(pe[10], pe[11]), cvtpk(pe[14], pe[15]));
                f1.u[1] = r.x; f1.u[3] = r.y;
                pa[sub][0] = f0.v;   // keys ksub*32 + 0..15
                pa[sub][1] = f1.v;   // keys ksub*32 + 16..31
            }

            // ---- O += P V ; l += P @ ones (bv shared by both subs) ----
            #pragma unroll
            for (int j = 0; j < 2; j++) {
                const int kbase = (ksub * 2 + j) * 16 + h8;
                const int vsw   = (l31 & 7) * 8;
                s8v bv0 = *(const s8v*)&Vs[cur][l31     ][kbase ^ vsw];
                s8v bv1 = *(const s8v*)&Vs[cur][32 + l31][kbase ^ vsw];
                __builtin_amdgcn_s_setprio(1);
                o[0][0] = __builtin_amdgcn_mfma_f32_32x32x16_bf16(pa[0][j], bv0, o[0][0], 0, 0, 0);
                o[0][1] = __builtin_amdgcn_mfma_f32_32x32x16_bf16(pa[0][j], bv1, o[0][1], 0, 0, 0);
                o[1][0] = __builtin_amdgcn_mfma_f32_32x32x16_bf16(pa[1][j], bv0, o[1][0], 0, 0, 0);
                o[1][1] = __builtin_amdgcn_mfma_f32_32x32x16_bf16(pa[1][j], bv1, o[1][1], 0, 0, 0);
                lc[0]   = __builtin_amdgcn_mfma_f32_32x32x16_bf16(pa[0][j], ones, lc[0], 0, 0, 0);
                lc[1]   = __builtin_amdgcn_mfma_f32_32x32x16_bf16(pa[1][j], ones, lc[1], 0, 0, 0);
                __builtin_amdgcn_s_setprio(0);
            }
        }

        __syncthreads();
    }

    // ---- normalize + write ao bf16 [m][1024]; lc layout == o layout ----
    #pragma unroll
    for (int sub = 0; sub < 2; sub++) {
        float inv[16];
        #pragma unroll
        for (int r = 0; r < 16; r++) inv[r] = 1.f / lc[sub][r];
        #pragma unroll
        for (int r = 0; r < 16; r++) {
            const int crow = (r & 3) + 8 * (r >> 2) + 4 * hi5;
            const int qrow = qb + sub * 32 + crow;
            const size_t base = ((size_t)b * N_ + qrow) * (H_ * DH_) + h * DH_;
            ao[base + l31]      = f2bf_fast(o[sub][0][r] * inv[r]);
            ao[base + 32 + l31] = f2bf_fast(o[sub][1][r] * inv[r]);
        }
    }
}

// ---------------------------------------------------------------------------
// Launch
// ---------------------------------------------------------------------------
extern "C" void kernel_launch(void* const* d_in, const int* in_sizes, int n_in,
                              void* d_out, int out_size, void* d_ws, size_t ws_size,
                              hipStream_t stream) {
    const float* x     = (const float*)d_in[0];   // [B,N,DIM]
    const float* w_qkv = (const float*)d_in[1];   // [3072, 1024]
    const float* w_out = (const float*)d_in[2];   // [1024, 1024]
    const float* b_out = (const float*)d_in[3];   // [1024]
    float* out = (float*)d_out;                   // [B,N,DIM] fp32

    char* ws = (char*)d_ws;
    unsigned short* x_bf    = (unsigned short*)(ws);                        // 16 MB
    unsigned short* wqkv_bf = (unsigned short*)(ws + (((size_t)16) << 20)); //  6 MB
    unsigned short* wout_bf = (unsigned short*)(ws + (((size_t)22) << 20)); //  2 MB
    unsigned short* qkv_bf  = (unsigned short*)(ws + (((size_t)24) << 20)); // 48 MB
    unsigned short* vT      = (unsigned short*)(ws + (((size_t)72) << 20)); // 16 MB
    unsigned short* ao_bf   = (unsigned short*)(ws + (((size_t)88) << 20)); // 16 MB

    const int M = B_ * N_;   // 8192

    // 0) input conversions fp32 -> bf16
    cvt_bf16<<<(M * DIM_) / 1024, 256, 0, stream>>>(x, x_bf, M * DIM_);
    cvt_bf16<<<(E3_ * DIM_) / 1024, 256, 0, stream>>>(w_qkv, wqkv_bf, E3_ * DIM_);
    cvt_bf16<<<(DIM_ * DIM_) / 1024, 256, 0, stream>>>(w_out, wout_bf, DIM_ * DIM_);

    // 1) QKV projection v2: 256x192x64 tiles, dbuf+prefetch, swizzled LDS
    {
        dim3 grid(E3_ / 192, M / 256);   // (16, 32) = 512 blocks
        gemm_qkv<<<grid, 512, 0, stream>>>(x_bf, wqkv_bf, qkv_bf, vT);
    }
    // 2) attention v9: 8 waves x 64 q-rows, lc-MFMA denominator, 1 block/CU
    {
        dim3 grid(N_ / 512, B_ * H_);    // (4, 64) = 256 blocks = 1/CU
        attn_mfma<<<grid, 512, 0, stream>>>(qkv_bf, vT, ao_bf);
    }
    // 3) out projection (bf16 MFMA, fp32 + bias out)
    {
        dim3 grid(DIM_ / 128, M / 128);  // (8, 64) = 512 blocks (%8==0)
        gemm_out<<<grid, 256, 0, stream>>>(ao_bf, wout_bf, b_out,
                                           out, M, DIM_, DIM_);
    }
    (void)in_sizes; (void)n_in; (void)out_size; (void)ws_size;
}